// Round 17
// baseline (240.491 us; speedup 1.0000x reference)
//
#include <hip/hip_runtime.h>
#include <hip/hip_fp16.h>
#include <math.h>

#define N_NODES 100000
#define N_EDGES 1600000
#define NEG_SLOPE 0.2f
#define EPS 1e-16f

// bucket sort geometry: 196 buckets of 512 nodes; 391 blocks x 4096 edges
#define NBUCK 196
#define CHUNK 4096
#define BLKB 391
#define EBUF_CAP 9216   // bucket mean 8192, sigma ~90; cap = mean+11sigma, global fallback

typedef _Float16 f16x8 __attribute__((ext_vector_type(8)));
typedef float f32x4 __attribute__((ext_vector_type(4)));

__device__ __forceinline__ float lrelu(float v) { return v > 0.f ? v : NEG_SLOPE * v; }

// load 4 halfs -> float4 (single 8B load)
__device__ __forceinline__ float4 ld4h(const __half* p) {
    uint2 r = *(const uint2*)p;
    __half2 h0 = *reinterpret_cast<const __half2*>(&r.x);
    __half2 h1 = *reinterpret_cast<const __half2*>(&r.y);
    float2 f0 = __half22float2(h0), f1 = __half22float2(h1);
    return make_float4(f0.x, f0.y, f1.x, f1.y);
}

// load 8 halfs -> 8 floats (single 16B load)
__device__ __forceinline__ void ld8h(const __half* p, float* f) {
    uint4 r = *(const uint4*)p;
    __half2 h0 = *reinterpret_cast<const __half2*>(&r.x);
    __half2 h1 = *reinterpret_cast<const __half2*>(&r.y);
    __half2 h2 = *reinterpret_cast<const __half2*>(&r.z);
    __half2 h3 = *reinterpret_cast<const __half2*>(&r.w);
    float2 f0 = __half22float2(h0), f1 = __half22float2(h1);
    float2 f2 = __half22float2(h2), f3 = __half22float2(h3);
    f[0] = f0.x; f[1] = f0.y; f[2] = f1.x; f[3] = f1.y;
    f[4] = f2.x; f[5] = f2.y; f[6] = f3.x; f[7] = f3.y;
}

// ---------------------------------------------------------------- Pass A (fused): coarse histogram + k_q + k_node1
__global__ void kA_hist_node(const int* __restrict__ ei, int* __restrict__ bh,
                             const float* __restrict__ x, const float* __restrict__ w1,
                             const float* __restrict__ as1, const float* __restrict__ ad1,
                             float* __restrict__ a1d, __half* __restrict__ p1h) {
    __shared__ int hist[NBUCK];
    __shared__ float qvs[24];
    int tid = threadIdx.x, b = blockIdx.x;
    if (tid < NBUCK) hist[tid] = 0;
    if (tid >= 224 && tid < 248) {          // threads 224..247 compute qv (disjoint from hist-zero range)
        int t = tid - 224;
        int c = t % 3, h = (t / 3) % 4, side = t / 12;
        const float* att = side ? ad1 : as1;
        float acc = 0.f;
        for (int cc = 0; cc < 32; cc++)
            acc += att[h * 32 + cc] * w1[(h * 32 + cc) * 3 + c];
        qvs[t] = acc;
    }
    __syncthreads();
    // node prep
    int n = b * 256 + tid;
    if (n < N_NODES) {
        float x0 = x[n * 3], x1 = x[n * 3 + 1], x2 = x[n * 3 + 2];
        float s0 = x0 * qvs[0]  + x1 * qvs[1]  + x2 * qvs[2];
        float s1 = x0 * qvs[3]  + x1 * qvs[4]  + x2 * qvs[5];
        float s2 = x0 * qvs[6]  + x1 * qvs[7]  + x2 * qvs[8];
        float s3 = x0 * qvs[9]  + x1 * qvs[10] + x2 * qvs[11];
        float4 d;
        d.x = x0 * qvs[12] + x1 * qvs[13] + x2 * qvs[14];
        d.y = x0 * qvs[15] + x1 * qvs[16] + x2 * qvs[17];
        d.z = x0 * qvs[18] + x1 * qvs[19] + x2 * qvs[20];
        d.w = x0 * qvs[21] + x1 * qvs[22] + x2 * qvs[23];
        ((float4*)a1d)[n] = d;
        __half2 h0 = __floats2half2_rn(s0, s1);
        __half2 h1 = __floats2half2_rn(s2, s3);
        __half2 h2v = __floats2half2_rn(x0, x1);
        __half2 h3 = __floats2half2_rn(x2, 1.f);
        uint4 st;
        st.x = *reinterpret_cast<unsigned int*>(&h0);
        st.y = *reinterpret_cast<unsigned int*>(&h1);
        st.z = *reinterpret_cast<unsigned int*>(&h2v);
        st.w = *reinterpret_cast<unsigned int*>(&h3);
        *reinterpret_cast<uint4*>(p1h + n * 8) = st;
    }
    // histogram
    int base = b * CHUNK;
    #pragma unroll
    for (int i = 0; i < CHUNK / 256; i++) {
        int e = base + i * 256 + tid;
        if (e < N_EDGES) {
            int dst = ei[N_EDGES + e];
            atomicAdd(&hist[dst >> 9], 1);
        }
    }
    __syncthreads();
    if (tid < NBUCK) bh[b * NBUCK + tid] = hist[tid];
}

// ---------------------------------------------------------------- S1: column scan of bh (one block per bucket)
__global__ void kS1(int* __restrict__ bh, int* __restrict__ bucketTot) {
    __shared__ int tsum[256];
    int k = blockIdx.x, t = threadIdx.x;
    int j0 = 2 * t, j1 = 2 * t + 1;
    int v0 = (j0 < BLKB) ? bh[j0 * NBUCK + k] : 0;
    int v1 = (j1 < BLKB) ? bh[j1 * NBUCK + k] : 0;
    int s = v0 + v1;
    tsum[t] = s;
    __syncthreads();
    for (int off = 1; off < 256; off <<= 1) {
        int tv = (t >= off) ? tsum[t - off] : 0;
        __syncthreads();
        tsum[t] += tv;
        __syncthreads();
    }
    int excl = tsum[t] - s;
    if (j0 < BLKB) bh[j0 * NBUCK + k] = excl;
    if (j1 < BLKB) bh[j1 * NBUCK + k] = excl + v0;
    if (t == 255) bucketTot[k] = tsum[255];
}

// ---------------------------------------------------------------- Pass B: bin edges by coarse bucket (self-scans bucket totals)
__global__ void kB_bin(const int* __restrict__ ei, const int* __restrict__ bh,
                       const int* __restrict__ bucketTot, int* __restrict__ binned) {
    __shared__ int cur[NBUCK];
    __shared__ int tmp[256];
    int tid = threadIdx.x, b = blockIdx.x;
    int v = (tid < NBUCK) ? bucketTot[tid] : 0;
    tmp[tid] = v;
    __syncthreads();
    for (int off = 1; off < 256; off <<= 1) {
        int tv = (tid >= off) ? tmp[tid - off] : 0;
        __syncthreads();
        tmp[tid] += tv;
        __syncthreads();
    }
    if (tid < NBUCK) cur[tid] = (tmp[tid] - v) + bh[b * NBUCK + tid];
    __syncthreads();
    int base = b * CHUNK;
    #pragma unroll
    for (int i = 0; i < CHUNK / 256; i++) {
        int e = base + i * 256 + tid;
        if (e < N_EDGES) {
            int src = ei[e], dst = ei[N_EDGES + e];
            int pos = atomicAdd(&cur[dst >> 9], 1);
            binned[pos] = src | ((dst & 511) << 17);
        }
    }
}

// ---------------------------------------------------------------- Pass C: per-bucket counting sort (LDS-staged, single binned read)
__global__ void kC_sort(const int* __restrict__ bucketTot, const int* __restrict__ binned,
                        int* __restrict__ deg, int* __restrict__ rowptr,
                        int* __restrict__ csr_src) {
    __shared__ int ebuf[EBUF_CAP];
    __shared__ int cnt[512];
    __shared__ int pfx[512];
    __shared__ int bsum[256];
    __shared__ int tmp[256];
    int t = threadIdx.x, k = blockIdx.x;
    int v = (t < NBUCK) ? bucketTot[t] : 0;
    tmp[t] = v;
    __syncthreads();
    for (int off = 1; off < 256; off <<= 1) {
        int tv = (t >= off) ? tmp[t - off] : 0;
        __syncthreads();
        tmp[t] += tv;
        __syncthreads();
    }
    int tot = bucketTot[k];
    int s0 = tmp[k] - tot, s1 = s0 + tot;    // tmp[k] broadcast (same-address)
    cnt[t] = 0; cnt[t + 256] = 0;
    __syncthreads();
    int m = s1 - s0;
    bool inl = (m <= EBUF_CAP);
    if (inl) {
        for (int i = t; i < m; i += 256) {
            int pkd = binned[s0 + i];
            ebuf[i] = pkd;
            atomicAdd(&cnt[pkd >> 17], 1);
        }
    } else {
        for (int i = s0 + t; i < s1; i += 256)
            atomicAdd(&cnt[binned[i] >> 17], 1);
    }
    __syncthreads();
    int a0 = cnt[2 * t], a1 = cnt[2 * t + 1];
    int s = a0 + a1;
    bsum[t] = s;
    __syncthreads();
    for (int off = 1; off < 256; off <<= 1) {
        int tv = (t >= off) ? bsum[t - off] : 0;
        __syncthreads();
        bsum[t] += tv;
        __syncthreads();
    }
    int excl = bsum[t] - s;
    pfx[2 * t] = excl;
    pfx[2 * t + 1] = excl + a0;
    int nb0 = k << 9;
    int n0 = nb0 + 2 * t, n1 = nb0 + 2 * t + 1;
    if (n0 < N_NODES) { deg[n0] = a0; rowptr[n0] = s0 + excl; }
    if (n1 < N_NODES) { deg[n1] = a1; rowptr[n1] = s0 + excl + a0; }
    __syncthreads();
    if (inl) {
        for (int i = t; i < m; i += 256) {
            int pkd = ebuf[i];
            int pos = s0 + atomicAdd(&pfx[pkd >> 17], 1);
            csr_src[pos] = pkd & 0x1FFFF;
        }
    } else {
        for (int i = s0 + t; i < s1; i += 256) {
            int pkd = binned[i];
            int pos = s0 + atomicAdd(&pfx[pkd >> 17], 1);
            csr_src[pos] = pkd & 0x1FFFF;
        }
    }
}

// ---------------------------------------------------------------- K-GAT1 v7: fp16 p1 rows (1 gather/edge) + MFMA phase B
#define G1_BLOCKS ((N_NODES + 63) / 64)
__global__ void k_gat1(const int* __restrict__ rowptr, const int* __restrict__ deg,
                       const int* __restrict__ csr_src,
                       const __half* __restrict__ p1h, const float* __restrict__ w1,
                       const float* __restrict__ a1d,
                       const float* __restrict__ b1, const float* __restrict__ w2,
                       const float* __restrict__ as2, const float* __restrict__ ad2,
                       __half* __restrict__ h2, float* __restrict__ a2s, float* __restrict__ a2d) {
    __shared__ float sm[64][16];                        // per-node: 4 heads x {s0,s1,s2,den}
    __shared__ __align__(16) __half F1h[4][16][136];    // per-wave f1, fp16, padded rows
    int tid = threadIdx.x;
    int wave = tid >> 6, lane = tid & 63;

    // ---- phase A: node = block*64 + wave*16 + (lane>>2); lane&3 = edge phase = head slot
    int nl = wave * 16 + (lane >> 2);
    int h  = lane & 3;
    int n  = blockIdx.x * 64 + nl;
    if (n < N_NODES) {
        float4 ad4 = ((const float4*)a1d)[n];          // broadcast across the quad
        float adv[4] = {ad4.x, ad4.y, ad4.z, ad4.w};
        int beg = rowptr[n], cnt = deg[n];
        float acc[4][4];                                // [head][{s0,s1,s2,den}]
        #pragma unroll
        for (int hh = 0; hh < 4; hh++)
            acc[hh][0] = acc[hh][1] = acc[hh][2] = acc[hh][3] = 0.f;
        int t = h;
        for (; t + 12 < cnt; t += 16) {                 // 4 edges/iter, 4 gathers in flight
            int i0 = csr_src[beg + t],     i1 = csr_src[beg + t + 4];
            int i2 = csr_src[beg + t + 8], i3 = csr_src[beg + t + 12];
            float g0[8], g1[8], g2[8], g3[8];
            ld8h(p1h + i0 * 8, g0);
            ld8h(p1h + i1 * 8, g1);
            ld8h(p1h + i2 * 8, g2);
            ld8h(p1h + i3 * 8, g3);
            #pragma unroll
            for (int hh = 0; hh < 4; hh++) {
                float e0 = __expf(lrelu(g0[hh] + adv[hh]));
                float e1 = __expf(lrelu(g1[hh] + adv[hh]));
                float e2 = __expf(lrelu(g2[hh] + adv[hh]));
                float e3 = __expf(lrelu(g3[hh] + adv[hh]));
                acc[hh][0] += e0 * g0[4] + e1 * g1[4] + e2 * g2[4] + e3 * g3[4];
                acc[hh][1] += e0 * g0[5] + e1 * g1[5] + e2 * g2[5] + e3 * g3[5];
                acc[hh][2] += e0 * g0[6] + e1 * g1[6] + e2 * g2[6] + e3 * g3[6];
                acc[hh][3] += e0 + e1 + e2 + e3;
            }
        }
        for (; t < cnt; t += 4) {                       // tail: up to 3 edges per lane
            int i0 = csr_src[beg + t];
            float g0[8];
            ld8h(p1h + i0 * 8, g0);
            #pragma unroll
            for (int hh = 0; hh < 4; hh++) {
                float e0 = __expf(lrelu(g0[hh] + adv[hh]));
                acc[hh][0] += e0 * g0[4];
                acc[hh][1] += e0 * g0[5];
                acc[hh][2] += e0 * g0[6];
                acc[hh][3] += e0;
            }
        }
        // 4-lane butterfly (quad is exec-uniform: same n) — every lane gets full sums
        #pragma unroll
        for (int hh = 0; hh < 4; hh++) {
            #pragma unroll
            for (int cc = 0; cc < 4; cc++) {
                float vv = acc[hh][cc];
                vv += __shfl_xor(vv, 1);
                vv += __shfl_xor(vv, 2);
                acc[hh][cc] = vv;
            }
        }
        float4 r;   // lane writes its own head's slice (static-index select, once per node)
        r.x = h == 0 ? acc[0][0] : h == 1 ? acc[1][0] : h == 2 ? acc[2][0] : acc[3][0];
        r.y = h == 0 ? acc[0][1] : h == 1 ? acc[1][1] : h == 2 ? acc[2][1] : acc[3][1];
        r.z = h == 0 ? acc[0][2] : h == 1 ? acc[1][2] : h == 2 ? acc[2][2] : acc[3][2];
        r.w = h == 0 ? acc[0][3] : h == 1 ? acc[1][3] : h == 2 ? acc[2][3] : acc[3][3];
        *(float4*)&sm[nl][h * 4] = r;
    }
    // same-wave LDS write->read below: no barrier needed

    // ---- B-fragments: Bf[tile][ks], lane elem e = w2[tile*16+(lane&15)][ks*32+(lane>>4)*8+e]
    f16x8 Bf[2][4];
    {
        int bn = lane & 15, bg = lane >> 4;
        #pragma unroll
        for (int tile = 0; tile < 2; tile++) {
            const float* wrow = w2 + (tile * 16 + bn) * 128 + bg * 8;
            #pragma unroll
            for (int ks = 0; ks < 4; ks++) {
                const float4* wp = (const float4*)(wrow + ks * 32);
                float4 u0 = wp[0], u1 = wp[1];
                f16x8 bf;
                bf[0] = (_Float16)u0.x; bf[1] = (_Float16)u0.y;
                bf[2] = (_Float16)u0.z; bf[3] = (_Float16)u0.w;
                bf[4] = (_Float16)u1.x; bf[5] = (_Float16)u1.y;
                bf[6] = (_Float16)u1.z; bf[7] = (_Float16)u1.w;
                Bf[tile][ks] = bf;
            }
        }
    }

    // ---- phase B step 1: f1 (fp16) for the wave's 16 nodes -> F1h
    int j = lane, j2 = lane + 64;
    int h0 = j >> 5;
    float wa0 = w1[j * 3], wa1 = w1[j * 3 + 1], wa2 = w1[j * 3 + 2];
    float wb0 = w1[j2 * 3], wb1 = w1[j2 * 3 + 1], wb2 = w1[j2 * 3 + 2];
    float b1j = b1[j], b1j2 = b1[j2];

    #pragma unroll 1
    for (int i = 0; i < 16; i++) {
        int n2 = blockIdx.x * 64 + wave * 16 + i;
        if (n2 >= N_NODES) break;
        const float* S = sm[wave * 16 + i];
        float v0 = (wa0 * S[h0 * 4] + wa1 * S[h0 * 4 + 1] + wa2 * S[h0 * 4 + 2])
                   / (S[h0 * 4 + 3] + EPS) + b1j;
        float v1 = (wb0 * S[(2 + h0) * 4] + wb1 * S[(2 + h0) * 4 + 1] + wb2 * S[(2 + h0) * 4 + 2])
                   / (S[(2 + h0) * 4 + 3] + EPS) + b1j2;
        float e0 = v0 > 0.f ? v0 : __expf(v0) - 1.f;   // ELU via fast exp
        float e1 = v1 > 0.f ? v1 : __expf(v1) - 1.f;
        F1h[wave][i][j]  = __float2half(e0);
        F1h[wave][i][j2] = __float2half(e1);
    }

    // ---- phase B step 2: 8 MFMA (2 col-tiles x 4 K-steps); A-frag via ds_read_b128
    f32x4 d0 = {0.f, 0.f, 0.f, 0.f}, d1 = {0.f, 0.f, 0.f, 0.f};
    {
        int am = lane & 15, ag = lane >> 4;
        const __half* Arow = &F1h[wave][am][0];
        #pragma unroll
        for (int ks = 0; ks < 4; ks++) {
            f16x8 af = *(const f16x8*)&Arow[ks * 32 + ag * 8];   // 16B-aligned
            d0 = __builtin_amdgcn_mfma_f32_16x16x32_f16(af, Bf[0][ks], d0, 0, 0, 0);
            d1 = __builtin_amdgcn_mfma_f32_16x16x32_f16(af, Bf[1][ks], d1, 0, 0, 0);
        }
    }

    // ---- epilogue: D col = lane&15 (channel), row = (lane>>4)*4+r (node)
    {
        int ch = lane & 15, rg = lane >> 4;
        float as2a = as2[ch], as2b = as2[ch + 16];
        float ad2a = ad2[ch], ad2b = ad2[ch + 16];
        #pragma unroll
        for (int r = 0; r < 4; r++) {
            int n2 = blockIdx.x * 64 + wave * 16 + rg * 4 + r;
            float va = d0[r], vb = d1[r];
            if (n2 < N_NODES) {
                h2[n2 * 32 + ch]      = __float2half(va);
                h2[n2 * 32 + ch + 16] = __float2half(vb);
            }
            float ps = va * as2a + vb * as2b;
            float pd = va * ad2a + vb * ad2b;
            ps += __shfl_xor(ps, 1); ps += __shfl_xor(ps, 2);
            ps += __shfl_xor(ps, 4); ps += __shfl_xor(ps, 8);
            pd += __shfl_xor(pd, 1); pd += __shfl_xor(pd, 2);
            pd += __shfl_xor(pd, 4); pd += __shfl_xor(pd, 8);
            if (ch == 0 && n2 < N_NODES) { a2s[n2] = ps; a2d[n2] = pd; }
        }
    }
}

// ---------------------------------------------------------------- K-GAT2 v6: bank-conflict-free LDS layouts
#define G2_BLOCKS ((N_NODES + 15) / 16)
__global__ void k_gat2(const int* __restrict__ rowptr, const int* __restrict__ deg,
                       const int* __restrict__ csr_src,
                       const __half* __restrict__ h2, const float* __restrict__ a2s,
                       const float* __restrict__ a2d, const float* __restrict__ b2,
                       const float* __restrict__ mw1, const float* __restrict__ mb1,
                       __half* __restrict__ u, __half* __restrict__ v) {
    __shared__ __align__(16) float WT[32][68];  // WT[k][slot]: slot s = half*32+c -> mw1[c][half*32+k]
    __shared__ int   pidx[4][68];               // per-wave staged idx, group stride 17
    __shared__ float pe[4][68];                 // per-wave staged e,   group stride 17
    __shared__ float hfv[4][144];               // per-wave hf, group row stride 36
    int tid = threadIdx.x;
    for (int i = tid; i < 2048; i += 256) {
        int s = i >> 5, k = i & 31;
        WT[k][s] = mw1[(s & 31) * 64 + (s >> 5) * 32 + k];
    }
    __syncthreads();
    int lane = tid & 63, w = tid >> 6;
    int nl = lane >> 4, sl = lane & 15;          // group (node) / sub-lane
    int eg2 = sl >> 2, qq = sl & 3;              // edge slot / 16-B chunk
    int n = blockIdx.x * 16 + w * 4 + nl;        // one node per group, no stride loop
    float4 b2a = ((const float4*)b2)[qq * 2];    // channels qq*8 .. qq*8+3
    float4 b2b = ((const float4*)b2)[qq * 2 + 1];// channels qq*8+4 .. qq*8+7

    int beg = 0, cnt = 0;
    float ad = 0.f;
    if (n < N_NODES) { beg = rowptr[n]; cnt = deg[n]; ad = a2d[n]; }

    float acc[8] = {0.f, 0.f, 0.f, 0.f, 0.f, 0.f, 0.f, 0.f};
    float den = 0.f;
    int pkbase = nl * 17;
    for (int b16 = 0; b16 < cnt; b16 += 16) {    // group-divergent, exec-masked
        int li = b16 + sl;
        int idx = (li < cnt) ? csr_src[beg + li] : 0;
        float e = 0.f;
        if (li < cnt) e = __expf(lrelu(a2s[idx] + ad));
        den += e;
        pidx[w][pkbase + sl] = idx;              // same-wave stage (<=2-way banks)
        pe[w][pkbase + sl]   = e;
        #pragma unroll
        for (int p = 0; p < 4; p++) {            // fixed 4 steps: 4 rows in flight/group
            int id = pidx[w][pkbase + p * 4 + eg2];
            float ee = pe[w][pkbase + p * 4 + eg2];  // 0 for pads
            float g[8];
            ld8h(h2 + id * 32 + qq * 8, g);      // 16-B gather (8 halfs)
            acc[0] += ee * g[0]; acc[1] += ee * g[1];
            acc[2] += ee * g[2]; acc[3] += ee * g[3];
            acc[4] += ee * g[4]; acc[5] += ee * g[5];
            acc[6] += ee * g[6]; acc[7] += ee * g[7];
        }
    }
    // reduce across the 4 edge slots (within 16-lane group)
    #pragma unroll
    for (int j = 0; j < 8; j++) {
        float vv = acc[j];
        vv += __shfl_xor(vv, 4);
        vv += __shfl_xor(vv, 8);
        acc[j] = vv;
    }
    den += __shfl_xor(den, 1); den += __shfl_xor(den, 2);
    den += __shfl_xor(den, 4); den += __shfl_xor(den, 8);
    float inv = 1.f / (den + EPS);
    if (sl < 4) {                                // sl<4 => eg2=0, qq=sl: owns hf[qq*8..+7]
        float4 ha, hb;
        ha.x = acc[0] * inv + b2a.x; ha.y = acc[1] * inv + b2a.y;
        ha.z = acc[2] * inv + b2a.z; ha.w = acc[3] * inv + b2a.w;
        hb.x = acc[4] * inv + b2b.x; hb.y = acc[5] * inv + b2b.y;
        hb.z = acc[6] * inv + b2b.z; hb.w = acc[7] * inv + b2b.w;
        *(float4*)&hfv[w][nl * 36 + sl * 8]     = ha;   // same-wave stage
        *(float4*)&hfv[w][nl * 36 + sl * 8 + 4] = hb;
    }
    // epilogue: lane sl owns output slots 4sl..4sl+3 (slot = half*32 + c)
    if (n < N_NODES) {
        int half_o = sl >> 3, c4 = (sl & 7) * 4;
        __half* outp = half_o ? v : u;
        float r0 = half_o ? 0.f : mb1[c4 + 0];
        float r1 = half_o ? 0.f : mb1[c4 + 1];
        float r2 = half_o ? 0.f : mb1[c4 + 2];
        float r3 = half_o ? 0.f : mb1[c4 + 3];
        const float* hfp = &hfv[w][nl * 36];
        int s4 = sl * 4;                         // slot base
        #pragma unroll
        for (int k = 0; k < 32; k++) {
            float hk = hfp[k];                   // group broadcast (4nl bank offset)
            float4 wv = *(const float4*)&WT[k][s4];  // consecutive slots: 2-way max
            r0 += wv.x * hk; r1 += wv.y * hk;
            r2 += wv.z * hk; r3 += wv.w * hk;
        }
        __half2 p0, p1;
        p0.x = __float2half(r0); p0.y = __float2half(r1);
        p1.x = __float2half(r2); p1.y = __float2half(r3);
        uint2 st;
        st.x = *reinterpret_cast<unsigned int*>(&p0);
        st.y = *reinterpret_cast<unsigned int*>(&p1);
        *reinterpret_cast<uint2*>(outp + n * 32 + c4) = st;  // 8-B aligned store
    }
}

// ---------------------------------------------------------------- K-MLP v2: 8 edges per 8-lane group per iter (2x chains in flight)
// Round-15 ambiguity: k_mlp at 46% HBM, occupancy 65% — latency- or BW-bound?
// v2 doubles in-flight gathers (16 loads/lane/iter, fully static unroll).
// Pre-committed read: latency-bound -> 43 -> ~31-35us; BW-bound -> null.
#define MLP_BLOCKS 4096
__global__ void k_mlp(const int* __restrict__ ei, const __half* __restrict__ u,
                      const __half* __restrict__ v, const float* __restrict__ mw2,
                      const float* __restrict__ mb2, float* __restrict__ out) {
    int tid = threadIdx.x;
    int q = tid & 7;
    float4 w2q = ((const float4*)mw2)[q];
    float mb20 = mb2[0];
    int g = blockIdx.x * 32 + (tid >> 3);
    const int stride = MLP_BLOCKS * 32 * 8;
    for (int e = g * 8; e < N_EDGES; e += stride) {
        int x0 = (e + 0 < N_EDGES) ? e + 0 : e;
        int x1 = (e + 1 < N_EDGES) ? e + 1 : e;
        int x2 = (e + 2 < N_EDGES) ? e + 2 : e;
        int x3 = (e + 3 < N_EDGES) ? e + 3 : e;
        int x4 = (e + 4 < N_EDGES) ? e + 4 : e;
        int x5 = (e + 5 < N_EDGES) ? e + 5 : e;
        int x6 = (e + 6 < N_EDGES) ? e + 6 : e;
        int x7 = (e + 7 < N_EDGES) ? e + 7 : e;
        int s0i = ei[x0], d0i = ei[N_EDGES + x0];
        int s1i = ei[x1], d1i = ei[N_EDGES + x1];
        int s2i = ei[x2], d2i = ei[N_EDGES + x2];
        int s3i = ei[x3], d3i = ei[N_EDGES + x3];
        int s4i = ei[x4], d4i = ei[N_EDGES + x4];
        int s5i = ei[x5], d5i = ei[N_EDGES + x5];
        int s6i = ei[x6], d6i = ei[N_EDGES + x6];
        int s7i = ei[x7], d7i = ei[N_EDGES + x7];
        float4 u0 = ld4h(u + s0i * 32 + q * 4), v0 = ld4h(v + d0i * 32 + q * 4);
        float4 u1 = ld4h(u + s1i * 32 + q * 4), v1 = ld4h(v + d1i * 32 + q * 4);
        float4 u2 = ld4h(u + s2i * 32 + q * 4), v2 = ld4h(v + d2i * 32 + q * 4);
        float4 u3 = ld4h(u + s3i * 32 + q * 4), v3 = ld4h(v + d3i * 32 + q * 4);
        float4 u4 = ld4h(u + s4i * 32 + q * 4), v4 = ld4h(v + d4i * 32 + q * 4);
        float4 u5 = ld4h(u + s5i * 32 + q * 4), v5 = ld4h(v + d5i * 32 + q * 4);
        float4 u6 = ld4h(u + s6i * 32 + q * 4), v6 = ld4h(v + d6i * 32 + q * 4);
        float4 u7 = ld4h(u + s7i * 32 + q * 4), v7 = ld4h(v + d7i * 32 + q * 4);
        float t0 = fmaxf(u0.x + v0.x, 0.f) * w2q.x + fmaxf(u0.y + v0.y, 0.f) * w2q.y
                 + fmaxf(u0.z + v0.z, 0.f) * w2q.z + fmaxf(u0.w + v0.w, 0.f) * w2q.w;
        float t1 = fmaxf(u1.x + v1.x, 0.f) * w2q.x + fmaxf(u1.y + v1.y, 0.f) * w2q.y
                 + fmaxf(u1.z + v1.z, 0.f) * w2q.z + fmaxf(u1.w + v1.w, 0.f) * w2q.w;
        float t2 = fmaxf(u2.x + v2.x, 0.f) * w2q.x + fmaxf(u2.y + v2.y, 0.f) * w2q.y
                 + fmaxf(u2.z + v2.z, 0.f) * w2q.z + fmaxf(u2.w + v2.w, 0.f) * w2q.w;
        float t3 = fmaxf(u3.x + v3.x, 0.f) * w2q.x + fmaxf(u3.y + v3.y, 0.f) * w2q.y
                 + fmaxf(u3.z + v3.z, 0.f) * w2q.z + fmaxf(u3.w + v3.w, 0.f) * w2q.w;
        float t4 = fmaxf(u4.x + v4.x, 0.f) * w2q.x + fmaxf(u4.y + v4.y, 0.f) * w2q.y
                 + fmaxf(u4.z + v4.z, 0.f) * w2q.z + fmaxf(u4.w + v4.w, 0.f) * w2q.w;
        float t5 = fmaxf(u5.x + v5.x, 0.f) * w2q.x + fmaxf(u5.y + v5.y, 0.f) * w2q.y
                 + fmaxf(u5.z + v5.z, 0.f) * w2q.z + fmaxf(u5.w + v5.w, 0.f) * w2q.w;
        float t6 = fmaxf(u6.x + v6.x, 0.f) * w2q.x + fmaxf(u6.y + v6.y, 0.f) * w2q.y
                 + fmaxf(u6.z + v6.z, 0.f) * w2q.z + fmaxf(u6.w + v6.w, 0.f) * w2q.w;
        float t7 = fmaxf(u7.x + v7.x, 0.f) * w2q.x + fmaxf(u7.y + v7.y, 0.f) * w2q.y
                 + fmaxf(u7.z + v7.z, 0.f) * w2q.z + fmaxf(u7.w + v7.w, 0.f) * w2q.w;
        t0 += __shfl_xor(t0, 1, 8); t0 += __shfl_xor(t0, 2, 8); t0 += __shfl_xor(t0, 4, 8);
        t1 += __shfl_xor(t1, 1, 8); t1 += __shfl_xor(t1, 2, 8); t1 += __shfl_xor(t1, 4, 8);
        t2 += __shfl_xor(t2, 1, 8); t2 += __shfl_xor(t2, 2, 8); t2 += __shfl_xor(t2, 4, 8);
        t3 += __shfl_xor(t3, 1, 8); t3 += __shfl_xor(t3, 2, 8); t3 += __shfl_xor(t3, 4, 8);
        t4 += __shfl_xor(t4, 1, 8); t4 += __shfl_xor(t4, 2, 8); t4 += __shfl_xor(t4, 4, 8);
        t5 += __shfl_xor(t5, 1, 8); t5 += __shfl_xor(t5, 2, 8); t5 += __shfl_xor(t5, 4, 8);
        t6 += __shfl_xor(t6, 1, 8); t6 += __shfl_xor(t6, 2, 8); t6 += __shfl_xor(t6, 4, 8);
        t7 += __shfl_xor(t7, 1, 8); t7 += __shfl_xor(t7, 2, 8); t7 += __shfl_xor(t7, 4, 8);
        if (q == 0) {
            out[x0] = fmaxf(t0 + mb20, 0.f);
            if (e + 1 < N_EDGES) out[x1] = fmaxf(t1 + mb20, 0.f);
            if (e + 2 < N_EDGES) out[x2] = fmaxf(t2 + mb20, 0.f);
            if (e + 3 < N_EDGES) out[x3] = fmaxf(t3 + mb20, 0.f);
            if (e + 4 < N_EDGES) out[x4] = fmaxf(t4 + mb20, 0.f);
            if (e + 5 < N_EDGES) out[x5] = fmaxf(t5 + mb20, 0.f);
            if (e + 6 < N_EDGES) out[x6] = fmaxf(t6 + mb20, 0.f);
            if (e + 7 < N_EDGES) out[x7] = fmaxf(t7 + mb20, 0.f);
        }
    }
}

// ---------------------------------------------------------------- launch
extern "C" void kernel_launch(void* const* d_in, const int* in_sizes, int n_in,
                              void* d_out, int out_size, void* d_ws, size_t ws_size,
                              hipStream_t stream) {
    const float* x    = (const float*)d_in[0];
    const int*   ei   = (const int*)d_in[1];
    const float* w1   = (const float*)d_in[2];
    const float* as1  = (const float*)d_in[3];
    const float* ad1  = (const float*)d_in[4];
    const float* b1   = (const float*)d_in[5];
    const float* w2   = (const float*)d_in[6];
    const float* as2  = (const float*)d_in[7];
    const float* ad2  = (const float*)d_in[8];
    const float* b2   = (const float*)d_in[9];
    const float* mw1  = (const float*)d_in[10];
    const float* mb1  = (const float*)d_in[11];
    const float* mw2  = (const float*)d_in[12];
    const float* mb2  = (const float*)d_in[13];
    float* out = (float*)d_out;

    // byte-offset workspace layout; p1h/h2/u/v 64B-aligned (offsets verified)
    char* base   = (char*)d_ws;
    int* deg     = (int*)(base);                      // N*4
    int* rowptr  = (int*)(base + 400000);             // N*4
    int* btot    = (int*)(base + 800000);             // NBUCK*4 (raw bucket totals)
    int* bh      = (int*)(base + 1200000);            // BLKB*NBUCK*4 = 306,544 B
    int* csr_src = (int*)(base + 1602048);            // E*4
    __half* p1h  = (__half*)(base + 8002048);         // 8N*2   (%64==0)
    float* a1d   = (float*)(base + 11202048);         // 4N*4
    __half* h2   = (__half*)(base + 12802048);        // 32N*2  (%64==0)
    int* binned  = (int*)(base + 19202048);           // E*4 (disjoint lifetime vs h2 region tail)
    float* a2s   = (float*)(base + 25602048);         // N*4
    float* a2d   = (float*)(base + 26002048);         // N*4
    __half* u    = (__half*)(base + 26402048);        // 32N*2  (%64==0)
    __half* v    = (__half*)(base + 32802048);        // 32N*2  (%64==0)

    kA_hist_node<<<BLKB, 256, 0, stream>>>(ei, bh, x, w1, as1, ad1, a1d, p1h);
    kS1<<<NBUCK, 256, 0, stream>>>(bh, btot);
    kB_bin<<<BLKB, 256, 0, stream>>>(ei, bh, btot, binned);
    kC_sort<<<NBUCK, 256, 0, stream>>>(btot, binned, deg, rowptr, csr_src);

    k_gat1<<<G1_BLOCKS, 256, 0, stream>>>(rowptr, deg, csr_src, p1h, w1, a1d,
                                          b1, w2, as2, ad2, h2, a2s, a2d);

    k_gat2<<<G2_BLOCKS, 256, 0, stream>>>(rowptr, deg, csr_src, h2, a2s, a2d, b2,
                                          mw1, mb1, u, v);

    k_mlp<<<MLP_BLOCKS, 256, 0, stream>>>(ei, u, v, mw2, mb2, out);
}

// Round 19
// 239.949 us; speedup vs baseline: 1.0023x; 1.0023x over previous
//
#include <hip/hip_runtime.h>
#include <hip/hip_fp16.h>
#include <math.h>

#define N_NODES 100000
#define N_EDGES 1600000
#define NEG_SLOPE 0.2f
#define EPS 1e-16f

// bucket sort geometry: 196 buckets of 512 nodes; 391 blocks x 4096 edges
#define NBUCK 196
#define CHUNK 4096
#define BLKB 391
#define EBUF_CAP 9216   // bucket mean 8192, sigma ~90; cap = mean+11sigma, global fallback

typedef _Float16 f16x8 __attribute__((ext_vector_type(8)));
typedef float f32x4 __attribute__((ext_vector_type(4)));

__device__ __forceinline__ float lrelu(float v) { return v > 0.f ? v : NEG_SLOPE * v; }

// load 4 halfs -> float4 (single 8B load)
__device__ __forceinline__ float4 ld4h(const __half* p) {
    uint2 r = *(const uint2*)p;
    __half2 h0 = *reinterpret_cast<const __half2*>(&r.x);
    __half2 h1 = *reinterpret_cast<const __half2*>(&r.y);
    float2 f0 = __half22float2(h0), f1 = __half22float2(h1);
    return make_float4(f0.x, f0.y, f1.x, f1.y);
}

// load 8 halfs -> 8 floats (single 16B load)
__device__ __forceinline__ void ld8h(const __half* p, float* f) {
    uint4 r = *(const uint4*)p;
    __half2 h0 = *reinterpret_cast<const __half2*>(&r.x);
    __half2 h1 = *reinterpret_cast<const __half2*>(&r.y);
    __half2 h2 = *reinterpret_cast<const __half2*>(&r.z);
    __half2 h3 = *reinterpret_cast<const __half2*>(&r.w);
    float2 f0 = __half22float2(h0), f1 = __half22float2(h1);
    float2 f2 = __half22float2(h2), f3 = __half22float2(h3);
    f[0] = f0.x; f[1] = f0.y; f[2] = f1.x; f[3] = f1.y;
    f[4] = f2.x; f[5] = f2.y; f[6] = f3.x; f[7] = f3.y;
}

// ---------------------------------------------------------------- Pass A (fused): coarse histogram + k_q + k_node1
__global__ void kA_hist_node(const int* __restrict__ ei, int* __restrict__ bh,
                             const float* __restrict__ x, const float* __restrict__ w1,
                             const float* __restrict__ as1, const float* __restrict__ ad1,
                             float* __restrict__ a1d, __half* __restrict__ p1h) {
    __shared__ int hist[NBUCK];
    __shared__ float qvs[24];
    int tid = threadIdx.x, b = blockIdx.x;
    if (tid < NBUCK) hist[tid] = 0;
    if (tid >= 224 && tid < 248) {          // threads 224..247 compute qv (disjoint from hist-zero range)
        int t = tid - 224;
        int c = t % 3, h = (t / 3) % 4, side = t / 12;
        const float* att = side ? ad1 : as1;
        float acc = 0.f;
        for (int cc = 0; cc < 32; cc++)
            acc += att[h * 32 + cc] * w1[(h * 32 + cc) * 3 + c];
        qvs[t] = acc;
    }
    __syncthreads();
    // node prep
    int n = b * 256 + tid;
    if (n < N_NODES) {
        float x0 = x[n * 3], x1 = x[n * 3 + 1], x2 = x[n * 3 + 2];
        float s0 = x0 * qvs[0]  + x1 * qvs[1]  + x2 * qvs[2];
        float s1 = x0 * qvs[3]  + x1 * qvs[4]  + x2 * qvs[5];
        float s2 = x0 * qvs[6]  + x1 * qvs[7]  + x2 * qvs[8];
        float s3 = x0 * qvs[9]  + x1 * qvs[10] + x2 * qvs[11];
        float4 d;
        d.x = x0 * qvs[12] + x1 * qvs[13] + x2 * qvs[14];
        d.y = x0 * qvs[15] + x1 * qvs[16] + x2 * qvs[17];
        d.z = x0 * qvs[18] + x1 * qvs[19] + x2 * qvs[20];
        d.w = x0 * qvs[21] + x1 * qvs[22] + x2 * qvs[23];
        ((float4*)a1d)[n] = d;
        __half2 h0 = __floats2half2_rn(s0, s1);
        __half2 h1 = __floats2half2_rn(s2, s3);
        __half2 h2v = __floats2half2_rn(x0, x1);
        __half2 h3 = __floats2half2_rn(x2, 1.f);
        uint4 st;
        st.x = *reinterpret_cast<unsigned int*>(&h0);
        st.y = *reinterpret_cast<unsigned int*>(&h1);
        st.z = *reinterpret_cast<unsigned int*>(&h2v);
        st.w = *reinterpret_cast<unsigned int*>(&h3);
        *reinterpret_cast<uint4*>(p1h + n * 8) = st;
    }
    // histogram
    int base = b * CHUNK;
    #pragma unroll
    for (int i = 0; i < CHUNK / 256; i++) {
        int e = base + i * 256 + tid;
        if (e < N_EDGES) {
            int dst = ei[N_EDGES + e];
            atomicAdd(&hist[dst >> 9], 1);
        }
    }
    __syncthreads();
    if (tid < NBUCK) bh[b * NBUCK + tid] = hist[tid];
}

// ---------------------------------------------------------------- S1: column scan of bh (one block per bucket)
__global__ void kS1(int* __restrict__ bh, int* __restrict__ bucketTot) {
    __shared__ int tsum[256];
    int k = blockIdx.x, t = threadIdx.x;
    int j0 = 2 * t, j1 = 2 * t + 1;
    int v0 = (j0 < BLKB) ? bh[j0 * NBUCK + k] : 0;
    int v1 = (j1 < BLKB) ? bh[j1 * NBUCK + k] : 0;
    int s = v0 + v1;
    tsum[t] = s;
    __syncthreads();
    for (int off = 1; off < 256; off <<= 1) {
        int tv = (t >= off) ? tsum[t - off] : 0;
        __syncthreads();
        tsum[t] += tv;
        __syncthreads();
    }
    int excl = tsum[t] - s;
    if (j0 < BLKB) bh[j0 * NBUCK + k] = excl;
    if (j1 < BLKB) bh[j1 * NBUCK + k] = excl + v0;
    if (t == 255) bucketTot[k] = tsum[255];
}

// ---------------------------------------------------------------- Pass B: bin edges by coarse bucket (self-scans bucket totals)
__global__ void kB_bin(const int* __restrict__ ei, const int* __restrict__ bh,
                       const int* __restrict__ bucketTot, int* __restrict__ binned) {
    __shared__ int cur[NBUCK];
    __shared__ int tmp[256];
    int tid = threadIdx.x, b = blockIdx.x;
    int v = (tid < NBUCK) ? bucketTot[tid] : 0;
    tmp[tid] = v;
    __syncthreads();
    for (int off = 1; off < 256; off <<= 1) {
        int tv = (tid >= off) ? tmp[tid - off] : 0;
        __syncthreads();
        tmp[tid] += tv;
        __syncthreads();
    }
    if (tid < NBUCK) cur[tid] = (tmp[tid] - v) + bh[b * NBUCK + tid];
    __syncthreads();
    int base = b * CHUNK;
    #pragma unroll
    for (int i = 0; i < CHUNK / 256; i++) {
        int e = base + i * 256 + tid;
        if (e < N_EDGES) {
            int src = ei[e], dst = ei[N_EDGES + e];
            int pos = atomicAdd(&cur[dst >> 9], 1);
            binned[pos] = src | ((dst & 511) << 17);
        }
    }
}

// ---------------------------------------------------------------- Pass C: per-bucket counting sort (LDS-staged, single binned read)
__global__ void kC_sort(const int* __restrict__ bucketTot, const int* __restrict__ binned,
                        int* __restrict__ deg, int* __restrict__ rowptr,
                        int* __restrict__ csr_src) {
    __shared__ int ebuf[EBUF_CAP];
    __shared__ int cnt[512];
    __shared__ int pfx[512];
    __shared__ int bsum[256];
    __shared__ int tmp[256];
    int t = threadIdx.x, k = blockIdx.x;
    int v = (t < NBUCK) ? bucketTot[t] : 0;
    tmp[t] = v;
    __syncthreads();
    for (int off = 1; off < 256; off <<= 1) {
        int tv = (t >= off) ? tmp[t - off] : 0;
        __syncthreads();
        tmp[t] += tv;
        __syncthreads();
    }
    int tot = bucketTot[k];
    int s0 = tmp[k] - tot, s1 = s0 + tot;    // tmp[k] broadcast (same-address)
    cnt[t] = 0; cnt[t + 256] = 0;
    __syncthreads();
    int m = s1 - s0;
    bool inl = (m <= EBUF_CAP);
    if (inl) {
        for (int i = t; i < m; i += 256) {
            int pkd = binned[s0 + i];
            ebuf[i] = pkd;
            atomicAdd(&cnt[pkd >> 17], 1);
        }
    } else {
        for (int i = s0 + t; i < s1; i += 256)
            atomicAdd(&cnt[binned[i] >> 17], 1);
    }
    __syncthreads();
    int a0 = cnt[2 * t], a1 = cnt[2 * t + 1];
    int s = a0 + a1;
    bsum[t] = s;
    __syncthreads();
    for (int off = 1; off < 256; off <<= 1) {
        int tv = (t >= off) ? bsum[t - off] : 0;
        __syncthreads();
        bsum[t] += tv;
        __syncthreads();
    }
    int excl = bsum[t] - s;
    pfx[2 * t] = excl;
    pfx[2 * t + 1] = excl + a0;
    int nb0 = k << 9;
    int n0 = nb0 + 2 * t, n1 = nb0 + 2 * t + 1;
    if (n0 < N_NODES) { deg[n0] = a0; rowptr[n0] = s0 + excl; }
    if (n1 < N_NODES) { deg[n1] = a1; rowptr[n1] = s0 + excl + a0; }
    __syncthreads();
    if (inl) {
        for (int i = t; i < m; i += 256) {
            int pkd = ebuf[i];
            int pos = s0 + atomicAdd(&pfx[pkd >> 17], 1);
            csr_src[pos] = pkd & 0x1FFFF;
        }
    } else {
        for (int i = s0 + t; i < s1; i += 256) {
            int pkd = binned[i];
            int pos = s0 + atomicAdd(&pfx[pkd >> 17], 1);
            csr_src[pos] = pkd & 0x1FFFF;
        }
    }
}

// ---------------------------------------------------------------- K-GAT1 v7: fp16 p1 rows (1 gather/edge) + MFMA phase B
#define G1_BLOCKS ((N_NODES + 63) / 64)
__global__ void k_gat1(const int* __restrict__ rowptr, const int* __restrict__ deg,
                       const int* __restrict__ csr_src,
                       const __half* __restrict__ p1h, const float* __restrict__ w1,
                       const float* __restrict__ a1d,
                       const float* __restrict__ b1, const float* __restrict__ w2,
                       const float* __restrict__ as2, const float* __restrict__ ad2,
                       __half* __restrict__ h2, float* __restrict__ a2s, float* __restrict__ a2d) {
    __shared__ float sm[64][16];                        // per-node: 4 heads x {s0,s1,s2,den}
    __shared__ __align__(16) __half F1h[4][16][136];    // per-wave f1, fp16, padded rows
    int tid = threadIdx.x;
    int wave = tid >> 6, lane = tid & 63;

    // ---- phase A: node = block*64 + wave*16 + (lane>>2); lane&3 = edge phase = head slot
    int nl = wave * 16 + (lane >> 2);
    int h  = lane & 3;
    int n  = blockIdx.x * 64 + nl;
    if (n < N_NODES) {
        float4 ad4 = ((const float4*)a1d)[n];          // broadcast across the quad
        float adv[4] = {ad4.x, ad4.y, ad4.z, ad4.w};
        int beg = rowptr[n], cnt = deg[n];
        float acc[4][4];                                // [head][{s0,s1,s2,den}]
        #pragma unroll
        for (int hh = 0; hh < 4; hh++)
            acc[hh][0] = acc[hh][1] = acc[hh][2] = acc[hh][3] = 0.f;
        int t = h;
        for (; t + 12 < cnt; t += 16) {                 // 4 edges/iter, 4 gathers in flight
            int i0 = csr_src[beg + t],     i1 = csr_src[beg + t + 4];
            int i2 = csr_src[beg + t + 8], i3 = csr_src[beg + t + 12];
            float g0[8], g1[8], g2[8], g3[8];
            ld8h(p1h + i0 * 8, g0);
            ld8h(p1h + i1 * 8, g1);
            ld8h(p1h + i2 * 8, g2);
            ld8h(p1h + i3 * 8, g3);
            #pragma unroll
            for (int hh = 0; hh < 4; hh++) {
                float e0 = __expf(lrelu(g0[hh] + adv[hh]));
                float e1 = __expf(lrelu(g1[hh] + adv[hh]));
                float e2 = __expf(lrelu(g2[hh] + adv[hh]));
                float e3 = __expf(lrelu(g3[hh] + adv[hh]));
                acc[hh][0] += e0 * g0[4] + e1 * g1[4] + e2 * g2[4] + e3 * g3[4];
                acc[hh][1] += e0 * g0[5] + e1 * g1[5] + e2 * g2[5] + e3 * g3[5];
                acc[hh][2] += e0 * g0[6] + e1 * g1[6] + e2 * g2[6] + e3 * g3[6];
                acc[hh][3] += e0 + e1 + e2 + e3;
            }
        }
        for (; t < cnt; t += 4) {                       // tail: up to 3 edges per lane
            int i0 = csr_src[beg + t];
            float g0[8];
            ld8h(p1h + i0 * 8, g0);
            #pragma unroll
            for (int hh = 0; hh < 4; hh++) {
                float e0 = __expf(lrelu(g0[hh] + adv[hh]));
                acc[hh][0] += e0 * g0[4];
                acc[hh][1] += e0 * g0[5];
                acc[hh][2] += e0 * g0[6];
                acc[hh][3] += e0;
            }
        }
        // 4-lane butterfly (quad is exec-uniform: same n) — every lane gets full sums
        #pragma unroll
        for (int hh = 0; hh < 4; hh++) {
            #pragma unroll
            for (int cc = 0; cc < 4; cc++) {
                float vv = acc[hh][cc];
                vv += __shfl_xor(vv, 1);
                vv += __shfl_xor(vv, 2);
                acc[hh][cc] = vv;
            }
        }
        float4 r;   // lane writes its own head's slice (static-index select, once per node)
        r.x = h == 0 ? acc[0][0] : h == 1 ? acc[1][0] : h == 2 ? acc[2][0] : acc[3][0];
        r.y = h == 0 ? acc[0][1] : h == 1 ? acc[1][1] : h == 2 ? acc[2][1] : acc[3][1];
        r.z = h == 0 ? acc[0][2] : h == 1 ? acc[1][2] : h == 2 ? acc[2][2] : acc[3][2];
        r.w = h == 0 ? acc[0][3] : h == 1 ? acc[1][3] : h == 2 ? acc[2][3] : acc[3][3];
        *(float4*)&sm[nl][h * 4] = r;
    }
    // same-wave LDS write->read below: no barrier needed

    // ---- B-fragments: Bf[tile][ks], lane elem e = w2[tile*16+(lane&15)][ks*32+(lane>>4)*8+e]
    f16x8 Bf[2][4];
    {
        int bn = lane & 15, bg = lane >> 4;
        #pragma unroll
        for (int tile = 0; tile < 2; tile++) {
            const float* wrow = w2 + (tile * 16 + bn) * 128 + bg * 8;
            #pragma unroll
            for (int ks = 0; ks < 4; ks++) {
                const float4* wp = (const float4*)(wrow + ks * 32);
                float4 u0 = wp[0], u1 = wp[1];
                f16x8 bf;
                bf[0] = (_Float16)u0.x; bf[1] = (_Float16)u0.y;
                bf[2] = (_Float16)u0.z; bf[3] = (_Float16)u0.w;
                bf[4] = (_Float16)u1.x; bf[5] = (_Float16)u1.y;
                bf[6] = (_Float16)u1.z; bf[7] = (_Float16)u1.w;
                Bf[tile][ks] = bf;
            }
        }
    }

    // ---- phase B step 1: f1 (fp16) for the wave's 16 nodes -> F1h
    int j = lane, j2 = lane + 64;
    int h0 = j >> 5;
    float wa0 = w1[j * 3], wa1 = w1[j * 3 + 1], wa2 = w1[j * 3 + 2];
    float wb0 = w1[j2 * 3], wb1 = w1[j2 * 3 + 1], wb2 = w1[j2 * 3 + 2];
    float b1j = b1[j], b1j2 = b1[j2];

    #pragma unroll 1
    for (int i = 0; i < 16; i++) {
        int n2 = blockIdx.x * 64 + wave * 16 + i;
        if (n2 >= N_NODES) break;
        const float* S = sm[wave * 16 + i];
        float v0 = (wa0 * S[h0 * 4] + wa1 * S[h0 * 4 + 1] + wa2 * S[h0 * 4 + 2])
                   / (S[h0 * 4 + 3] + EPS) + b1j;
        float v1 = (wb0 * S[(2 + h0) * 4] + wb1 * S[(2 + h0) * 4 + 1] + wb2 * S[(2 + h0) * 4 + 2])
                   / (S[(2 + h0) * 4 + 3] + EPS) + b1j2;
        float e0 = v0 > 0.f ? v0 : __expf(v0) - 1.f;   // ELU via fast exp
        float e1 = v1 > 0.f ? v1 : __expf(v1) - 1.f;
        F1h[wave][i][j]  = __float2half(e0);
        F1h[wave][i][j2] = __float2half(e1);
    }

    // ---- phase B step 2: 8 MFMA (2 col-tiles x 4 K-steps); A-frag via ds_read_b128
    f32x4 d0 = {0.f, 0.f, 0.f, 0.f}, d1 = {0.f, 0.f, 0.f, 0.f};
    {
        int am = lane & 15, ag = lane >> 4;
        const __half* Arow = &F1h[wave][am][0];
        #pragma unroll
        for (int ks = 0; ks < 4; ks++) {
            f16x8 af = *(const f16x8*)&Arow[ks * 32 + ag * 8];   // 16B-aligned
            d0 = __builtin_amdgcn_mfma_f32_16x16x32_f16(af, Bf[0][ks], d0, 0, 0, 0);
            d1 = __builtin_amdgcn_mfma_f32_16x16x32_f16(af, Bf[1][ks], d1, 0, 0, 0);
        }
    }

    // ---- epilogue: D col = lane&15 (channel), row = (lane>>4)*4+r (node)
    {
        int ch = lane & 15, rg = lane >> 4;
        float as2a = as2[ch], as2b = as2[ch + 16];
        float ad2a = ad2[ch], ad2b = ad2[ch + 16];
        #pragma unroll
        for (int r = 0; r < 4; r++) {
            int n2 = blockIdx.x * 64 + wave * 16 + rg * 4 + r;
            float va = d0[r], vb = d1[r];
            if (n2 < N_NODES) {
                h2[n2 * 32 + ch]      = __float2half(va);
                h2[n2 * 32 + ch + 16] = __float2half(vb);
            }
            float ps = va * as2a + vb * as2b;
            float pd = va * ad2a + vb * ad2b;
            ps += __shfl_xor(ps, 1); ps += __shfl_xor(ps, 2);
            ps += __shfl_xor(ps, 4); ps += __shfl_xor(ps, 8);
            pd += __shfl_xor(pd, 1); pd += __shfl_xor(pd, 2);
            pd += __shfl_xor(pd, 4); pd += __shfl_xor(pd, 8);
            if (ch == 0 && n2 < N_NODES) { a2s[n2] = ps; a2d[n2] = pd; }
        }
    }
}

// ---------------------------------------------------------------- K-GAT2 v6: bank-conflict-free LDS layouts
#define G2_BLOCKS ((N_NODES + 15) / 16)
__global__ void k_gat2(const int* __restrict__ rowptr, const int* __restrict__ deg,
                       const int* __restrict__ csr_src,
                       const __half* __restrict__ h2, const float* __restrict__ a2s,
                       const float* __restrict__ a2d, const float* __restrict__ b2,
                       const float* __restrict__ mw1, const float* __restrict__ mb1,
                       __half* __restrict__ u, __half* __restrict__ v) {
    __shared__ __align__(16) float WT[32][68];  // WT[k][slot]: slot s = half*32+c -> mw1[c][half*32+k]
    __shared__ int   pidx[4][68];               // per-wave staged idx, group stride 17
    __shared__ float pe[4][68];                 // per-wave staged e,   group stride 17
    __shared__ float hfv[4][144];               // per-wave hf, group row stride 36
    int tid = threadIdx.x;
    for (int i = tid; i < 2048; i += 256) {
        int s = i >> 5, k = i & 31;
        WT[k][s] = mw1[(s & 31) * 64 + (s >> 5) * 32 + k];
    }
    __syncthreads();
    int lane = tid & 63, w = tid >> 6;
    int nl = lane >> 4, sl = lane & 15;          // group (node) / sub-lane
    int eg2 = sl >> 2, qq = sl & 3;              // edge slot / 16-B chunk
    int n = blockIdx.x * 16 + w * 4 + nl;        // one node per group, no stride loop
    float4 b2a = ((const float4*)b2)[qq * 2];    // channels qq*8 .. qq*8+3
    float4 b2b = ((const float4*)b2)[qq * 2 + 1];// channels qq*8+4 .. qq*8+7

    int beg = 0, cnt = 0;
    float ad = 0.f;
    if (n < N_NODES) { beg = rowptr[n]; cnt = deg[n]; ad = a2d[n]; }

    float acc[8] = {0.f, 0.f, 0.f, 0.f, 0.f, 0.f, 0.f, 0.f};
    float den = 0.f;
    int pkbase = nl * 17;
    for (int b16 = 0; b16 < cnt; b16 += 16) {    // group-divergent, exec-masked
        int li = b16 + sl;
        int idx = (li < cnt) ? csr_src[beg + li] : 0;
        float e = 0.f;
        if (li < cnt) e = __expf(lrelu(a2s[idx] + ad));
        den += e;
        pidx[w][pkbase + sl] = idx;              // same-wave stage (<=2-way banks)
        pe[w][pkbase + sl]   = e;
        #pragma unroll
        for (int p = 0; p < 4; p++) {            // fixed 4 steps: 4 rows in flight/group
            int id = pidx[w][pkbase + p * 4 + eg2];
            float ee = pe[w][pkbase + p * 4 + eg2];  // 0 for pads
            float g[8];
            ld8h(h2 + id * 32 + qq * 8, g);      // 16-B gather (8 halfs)
            acc[0] += ee * g[0]; acc[1] += ee * g[1];
            acc[2] += ee * g[2]; acc[3] += ee * g[3];
            acc[4] += ee * g[4]; acc[5] += ee * g[5];
            acc[6] += ee * g[6]; acc[7] += ee * g[7];
        }
    }
    // reduce across the 4 edge slots (within 16-lane group)
    #pragma unroll
    for (int j = 0; j < 8; j++) {
        float vv = acc[j];
        vv += __shfl_xor(vv, 4);
        vv += __shfl_xor(vv, 8);
        acc[j] = vv;
    }
    den += __shfl_xor(den, 1); den += __shfl_xor(den, 2);
    den += __shfl_xor(den, 4); den += __shfl_xor(den, 8);
    float inv = 1.f / (den + EPS);
    if (sl < 4) {                                // sl<4 => eg2=0, qq=sl: owns hf[qq*8..+7]
        float4 ha, hb;
        ha.x = acc[0] * inv + b2a.x; ha.y = acc[1] * inv + b2a.y;
        ha.z = acc[2] * inv + b2a.z; ha.w = acc[3] * inv + b2a.w;
        hb.x = acc[4] * inv + b2b.x; hb.y = acc[5] * inv + b2b.y;
        hb.z = acc[6] * inv + b2b.z; hb.w = acc[7] * inv + b2b.w;
        *(float4*)&hfv[w][nl * 36 + sl * 8]     = ha;   // same-wave stage
        *(float4*)&hfv[w][nl * 36 + sl * 8 + 4] = hb;
    }
    // epilogue: lane sl owns output slots 4sl..4sl+3 (slot = half*32 + c)
    if (n < N_NODES) {
        int half_o = sl >> 3, c4 = (sl & 7) * 4;
        __half* outp = half_o ? v : u;
        float r0 = half_o ? 0.f : mb1[c4 + 0];
        float r1 = half_o ? 0.f : mb1[c4 + 1];
        float r2 = half_o ? 0.f : mb1[c4 + 2];
        float r3 = half_o ? 0.f : mb1[c4 + 3];
        const float* hfp = &hfv[w][nl * 36];
        int s4 = sl * 4;                         // slot base
        #pragma unroll
        for (int k = 0; k < 32; k++) {
            float hk = hfp[k];                   // group broadcast (4nl bank offset)
            float4 wv = *(const float4*)&WT[k][s4];  // consecutive slots: 2-way max
            r0 += wv.x * hk; r1 += wv.y * hk;
            r2 += wv.z * hk; r3 += wv.w * hk;
        }
        __half2 p0, p1;
        p0.x = __float2half(r0); p0.y = __float2half(r1);
        p1.x = __float2half(r2); p1.y = __float2half(r3);
        uint2 st;
        st.x = *reinterpret_cast<unsigned int*>(&p0);
        st.y = *reinterpret_cast<unsigned int*>(&p1);
        *reinterpret_cast<uint2*>(outp + n * 32 + c4) = st;  // 8-B aligned store
    }
}

// ---------------------------------------------------------------- K-MLP: 8 lanes/edge, 4 edges/iter, fp16 u/v rows (1 line each)
// (v2 8-edge variant A/B'd in round 16: null/regression -> BW-bound; reverted)
#define MLP_BLOCKS 4096
__global__ void k_mlp(const int* __restrict__ ei, const __half* __restrict__ u,
                      const __half* __restrict__ v, const float* __restrict__ mw2,
                      const float* __restrict__ mb2, float* __restrict__ out) {
    int tid = threadIdx.x;
    int q = tid & 7;
    float4 w2q = ((const float4*)mw2)[q];
    float mb20 = mb2[0];
    int g = blockIdx.x * 32 + (tid >> 3);
    const int stride = MLP_BLOCKS * 32 * 4;
    for (int e = g * 4; e < N_EDGES; e += stride) {
        int eb = e;
        int e1 = (eb + 1 < N_EDGES) ? eb + 1 : eb;
        int e2 = (eb + 2 < N_EDGES) ? eb + 2 : eb;
        int e3 = (eb + 3 < N_EDGES) ? eb + 3 : eb;
        int sa = ei[eb], da = ei[N_EDGES + eb];
        int sb = ei[e1], db = ei[N_EDGES + e1];
        int sc = ei[e2], dc = ei[N_EDGES + e2];
        int sd = ei[e3], dd = ei[N_EDGES + e3];
        float4 ua = ld4h(u + sa * 32 + q * 4);
        float4 va = ld4h(v + da * 32 + q * 4);
        float4 ub = ld4h(u + sb * 32 + q * 4);
        float4 vb = ld4h(v + db * 32 + q * 4);
        float4 uc = ld4h(u + sc * 32 + q * 4);
        float4 vc = ld4h(v + dc * 32 + q * 4);
        float4 ud = ld4h(u + sd * 32 + q * 4);
        float4 vd = ld4h(v + dd * 32 + q * 4);
        float s0 = fmaxf(ua.x + va.x, 0.f) * w2q.x + fmaxf(ua.y + va.y, 0.f) * w2q.y
                 + fmaxf(ua.z + va.z, 0.f) * w2q.z + fmaxf(ua.w + va.w, 0.f) * w2q.w;
        float s1 = fmaxf(ub.x + vb.x, 0.f) * w2q.x + fmaxf(ub.y + vb.y, 0.f) * w2q.y
                 + fmaxf(ub.z + vb.z, 0.f) * w2q.z + fmaxf(ub.w + vb.w, 0.f) * w2q.w;
        float s2 = fmaxf(uc.x + vc.x, 0.f) * w2q.x + fmaxf(uc.y + vc.y, 0.f) * w2q.y
                 + fmaxf(uc.z + vc.z, 0.f) * w2q.z + fmaxf(uc.w + vc.w, 0.f) * w2q.w;
        float s3 = fmaxf(ud.x + vd.x, 0.f) * w2q.x + fmaxf(ud.y + vd.y, 0.f) * w2q.y
                 + fmaxf(ud.z + vd.z, 0.f) * w2q.z + fmaxf(ud.w + vd.w, 0.f) * w2q.w;
        s0 += __shfl_xor(s0, 1, 8); s0 += __shfl_xor(s0, 2, 8); s0 += __shfl_xor(s0, 4, 8);
        s1 += __shfl_xor(s1, 1, 8); s1 += __shfl_xor(s1, 2, 8); s1 += __shfl_xor(s1, 4, 8);
        s2 += __shfl_xor(s2, 1, 8); s2 += __shfl_xor(s2, 2, 8); s2 += __shfl_xor(s2, 4, 8);
        s3 += __shfl_xor(s3, 1, 8); s3 += __shfl_xor(s3, 2, 8); s3 += __shfl_xor(s3, 4, 8);
        if (q == 0) {
            out[eb] = fmaxf(s0 + mb20, 0.f);
            if (eb + 1 < N_EDGES) out[eb + 1] = fmaxf(s1 + mb20, 0.f);
            if (eb + 2 < N_EDGES) out[eb + 2] = fmaxf(s2 + mb20, 0.f);
            if (eb + 3 < N_EDGES) out[eb + 3] = fmaxf(s3 + mb20, 0.f);
        }
    }
}

// ---------------------------------------------------------------- launch
extern "C" void kernel_launch(void* const* d_in, const int* in_sizes, int n_in,
                              void* d_out, int out_size, void* d_ws, size_t ws_size,
                              hipStream_t stream) {
    const float* x    = (const float*)d_in[0];
    const int*   ei   = (const int*)d_in[1];
    const float* w1   = (const float*)d_in[2];
    const float* as1  = (const float*)d_in[3];
    const float* ad1  = (const float*)d_in[4];
    const float* b1   = (const float*)d_in[5];
    const float* w2   = (const float*)d_in[6];
    const float* as2  = (const float*)d_in[7];
    const float* ad2  = (const float*)d_in[8];
    const float* b2   = (const float*)d_in[9];
    const float* mw1  = (const float*)d_in[10];
    const float* mb1  = (const float*)d_in[11];
    const float* mw2  = (const float*)d_in[12];
    const float* mb2  = (const float*)d_in[13];
    float* out = (float*)d_out;

    // byte-offset workspace layout; p1h/h2/u/v 64B-aligned (offsets verified)
    char* base   = (char*)d_ws;
    int* deg     = (int*)(base);                      // N*4
    int* rowptr  = (int*)(base + 400000);             // N*4
    int* btot    = (int*)(base + 800000);             // NBUCK*4 (raw bucket totals)
    int* bh      = (int*)(base + 1200000);            // BLKB*NBUCK*4 = 306,544 B
    int* csr_src = (int*)(base + 1602048);            // E*4
    __half* p1h  = (__half*)(base + 8002048);         // 8N*2   (%64==0)
    float* a1d   = (float*)(base + 11202048);         // 4N*4
    __half* h2   = (__half*)(base + 12802048);        // 32N*2  (%64==0)
    int* binned  = (int*)(base + 19202048);           // E*4 (disjoint lifetime vs h2 region tail)
    float* a2s   = (float*)(base + 25602048);         // N*4
    float* a2d   = (float*)(base + 26002048);         // N*4
    __half* u    = (__half*)(base + 26402048);        // 32N*2  (%64==0)
    __half* v    = (__half*)(base + 32802048);        // 32N*2  (%64==0)

    kA_hist_node<<<BLKB, 256, 0, stream>>>(ei, bh, x, w1, as1, ad1, a1d, p1h);
    kS1<<<NBUCK, 256, 0, stream>>>(bh, btot);
    kB_bin<<<BLKB, 256, 0, stream>>>(ei, bh, btot, binned);
    kC_sort<<<NBUCK, 256, 0, stream>>>(btot, binned, deg, rowptr, csr_src);

    k_gat1<<<G1_BLOCKS, 256, 0, stream>>>(rowptr, deg, csr_src, p1h, w1, a1d,
                                          b1, w2, as2, ad2, h2, a2s, a2d);

    k_gat2<<<G2_BLOCKS, 256, 0, stream>>>(rowptr, deg, csr_src, h2, a2s, a2d, b2,
                                          mw1, mb1, u, v);

    k_mlp<<<MLP_BLOCKS, 256, 0, stream>>>(ei, u, v, mw2, mb2, out);
}